// Round 5
// baseline (371.801 us; speedup 1.0000x reference)
//
#include <hip/hip_runtime.h>

#define IN_F 4096
#define OUT_F 4096
#define RANK 16
#define NTOK 8192
#define KP 4160            // IN_F + 16 lora cols + 48 zero pad = 65 * 64
#define BK 64
#define NT (KP / BK)       // 65
#define BM 256
#define BN 256

typedef __bf16 bf16x8 __attribute__((ext_vector_type(8)));
typedef float f32x4 __attribute__((ext_vector_type(4)));
typedef float f32x16 __attribute__((ext_vector_type(16)));

__device__ __forceinline__ unsigned short f2bf(float f) {
  unsigned int u = __float_as_uint(f);
  u += 0x7fffu + ((u >> 16) & 1u);   // round-to-nearest-even
  return (unsigned short)(u >> 16);
}

__device__ __forceinline__ void async_ld16(const void* g, void* l) {
  __builtin_amdgcn_global_load_lds(
      (const __attribute__((address_space(1))) unsigned int*)g,
      (__attribute__((address_space(3))) unsigned int*)l, 16, 0, 0);
}

__device__ const float NF4_TAB[16] = {
    -1.0f, -0.6961928009986877f, -0.5250730514526367f, -0.39491748809814453f,
    -0.28444138169288635f, -0.18477343022823334f, -0.09105003625154495f, 0.0f,
    0.07958029955625534f, 0.16093020141124725f, 0.24611230194568634f,
    0.33791524171829224f, 0.44070982933044434f, 0.5626170039176941f,
    0.7229568362236023f, 1.0f};

// ---------------- K1: x -> bf16 A', fused lora_down t = x @ Ld^T ----------------
__global__ __launch_bounds__(256) void k_prep_a(
    const float* __restrict__ x, const float* __restrict__ ldw,
    unsigned short* __restrict__ Ap) {
  const int tid = threadIdx.x;
  const int lane = tid & 63;
  const int w = tid >> 6;
  const int m0 = blockIdx.x * 4;

  float acc[4][4];
#pragma unroll
  for (int i = 0; i < 4; ++i)
#pragma unroll
    for (int rl = 0; rl < 4; ++rl) acc[i][rl] = 0.f;

  for (int c = 0; c < 16; ++c) {
    const int k0 = (c * 64 + lane) * 4;
    float4 xv[4];
#pragma unroll
    for (int i = 0; i < 4; ++i) {
      xv[i] = *(const float4*)&x[(size_t)(m0 + i) * IN_F + k0];
      if (w == i) {  // wave i writes row i's bf16 conversion (balanced)
        ushort4 s;
        s.x = f2bf(xv[i].x); s.y = f2bf(xv[i].y);
        s.z = f2bf(xv[i].z); s.w = f2bf(xv[i].w);
        *(ushort4*)&Ap[(size_t)(m0 + i) * KP + k0] = s;
      }
    }
#pragma unroll
    for (int rl = 0; rl < 4; ++rl) {
      float4 lv = *(const float4*)&ldw[(size_t)(w * 4 + rl) * IN_F + k0];
#pragma unroll
      for (int i = 0; i < 4; ++i)
        acc[i][rl] += xv[i].x * lv.x + xv[i].y * lv.y + xv[i].z * lv.z +
                      xv[i].w * lv.w;
    }
  }
#pragma unroll
  for (int i = 0; i < 4; ++i)
#pragma unroll
    for (int rl = 0; rl < 4; ++rl) {
      float v = acc[i][rl];
#pragma unroll
      for (int m = 1; m < 64; m <<= 1) v += __shfl_xor(v, m, 64);
      acc[i][rl] = v;
    }
  __shared__ float red[4][16];
  if (lane == 0) {
#pragma unroll
    for (int i = 0; i < 4; ++i)
#pragma unroll
      for (int rl = 0; rl < 4; ++rl) red[i][w * 4 + rl] = acc[i][rl];
  }
  __syncthreads();
  if (tid < 64) {  // lora columns 4096..4111
    Ap[(size_t)(m0 + (tid >> 4)) * KP + IN_F + (tid & 15)] =
        f2bf(red[tid >> 4][tid & 15]);
  } else {  // zero pad cols 4112..4159 : 4 rows x 48 cols = 192 elems
    const int t2 = tid - 64;
    if (t2 < 192)
      Ap[(size_t)(m0 + t2 / 48) * KP + IN_F + 16 + (t2 % 48)] = 0;
  }
}

// ---------------- K2: NF4 dequant -> bf16 B', append Lu*(alpha/r) ----------------
__global__ __launch_bounds__(256) void k_prep_b(
    const int* __restrict__ q, const float* __restrict__ amax,
    const float* __restrict__ luw, const float* __restrict__ alpha,
    unsigned short* __restrict__ Bp) {
  __shared__ float tab[16];
  const int tid = threadIdx.x;
  const int n = blockIdx.x;
  if (tid < 16) tab[tid] = NF4_TAB[tid];
  __syncthreads();
#pragma unroll
  for (int c = 0; c < 4; ++c) {
    const int k0 = (tid + 256 * c) * 4;
    int4 qv = *(const int4*)&q[(size_t)n * IN_F + k0];
    float am = amax[n * (IN_F / 64) + (k0 >> 6)];
    ushort4 s;
    s.x = f2bf(tab[qv.x] * am);
    s.y = f2bf(tab[qv.y] * am);
    s.z = f2bf(tab[qv.z] * am);
    s.w = f2bf(tab[qv.w] * am);
    *(ushort4*)&Bp[(size_t)n * KP + k0] = s;
  }
  if (tid < RANK) {
    float sc = alpha[0] * (1.0f / RANK);
    Bp[(size_t)n * KP + IN_F + tid] = f2bf(luw[n * RANK + tid] * sc);
  } else if (tid < 64) {  // zero pad cols 4112..4159
    Bp[(size_t)n * KP + IN_F + tid] = 0;
  }
}

// ---------------- K3: 256x256 8-phase bf16 MFMA GEMM (32x32x16) ----------------
// C[m,n] = sum_k A'[m,k] * B'[n,k] + bias[n]
// 8 waves = 2M x 4N, per-wave 128x64 output = 4 (tm) x 2 (tn) tiles of 32x32.
// BK=64 -> 4 k-slices of 16. LDS: 2 dbuf x 4 half-tile regions [128][64] bf16
// = 128 KiB. T2 swizzle (3-bit, 16B-slot): LDS slot = global_slot ^ (row&7).
// Staging schedule (round-3 measured-best): ph0->B2(t+1), ph1->B3(t+1),
// ph2->A0(t+2), ph3->A1(t+2); one counted wait vmcnt(4) per K-tile.
// Race-safety: A regions of buf fully read after ph1 barrier; B regions after
// ph2 barrier; staged targets are always past their last reader.
__global__ __launch_bounds__(512, 1) void k_gemm(
    const unsigned short* __restrict__ Ap, const unsigned short* __restrict__ Bp,
    const float* __restrict__ bias, float* __restrict__ out) {
  __shared__ unsigned short lds[65536];  // 128 KiB
  const int tid = threadIdx.x;
  const int lane = tid & 63;
  const int w = tid >> 6;
  const int wr = w >> 2;       // 0..1  (M half)
  const int wc = w & 3;        // 0..3  (N quarter)

  // T1: XCD-aware block swizzle (nwg = 512, divisible by 8)
  const int nwg = gridDim.x * gridDim.y;           // 512
  const int flat = blockIdx.y * gridDim.x + blockIdx.x;
  const int cpx = nwg >> 3;
  const int swz = (flat & 7) * cpx + (flat >> 3);
  const int m0 = (swz / (OUT_F / BN)) * BM;
  const int n0 = (swz % (OUT_F / BN)) * BN;

  // staging: wave w covers half-tile rows w*16 + i*8 + (lane>>3), i=0,1
  // source col slot pre-swizzled: slot_src = (lane&7) ^ (row&7)
  const int srow = lane >> 3;                       // 0..7
  const int scol = (((lane & 7) ^ srow) << 3);      // bf16 elems
  const unsigned short* gA = Ap + (size_t)(m0 + (w << 4) + srow) * KP + scol;
  const unsigned short* gB = Bp + (size_t)(n0 + (w << 4) + srow) * KP + scol;
  unsigned short* const ldsw = lds + (w << 10);     // wave-uniform dest base

  // 32x32x16 fragment read: row = lane&31, k = (lane>>5)*8 + 0..7 within
  // slice s (k-slot = s*2 | hi). Swizzled slot = raw_slot ^ (row&7).
  const int rowA = (lane & 31) << 6;   // row * 64 shorts
  const int hi = lane >> 5;            // 0..1
  const int sw = lane & 7;             // row&7

#define STAGE2(tt, ht, cond)                                                   \
  if (cond) {                                                                  \
    const unsigned short* s_ =                                                 \
        ((ht) < 2 ? gA + (size_t)((ht) << 7) * KP                              \
                  : gB + (size_t)(((ht)-2) << 7) * KP) + (size_t)(tt)*BK;      \
    unsigned short* d_ = ldsw + ((((tt)&1) << 15) + ((ht) << 13));             \
    async_ld16(s_, d_);                                                        \
    async_ld16(s_ + (size_t)8 * KP, d_ + 512);                                 \
  }

#define LDA32(bsel, tm, s)                                                     \
  (*(const bf16x8*)&lds[((bsel) << 15) + (wr << 13) + ((tm) << 11) + rowA +    \
                        (((((s) << 1) | hi) ^ sw) << 3)])
#define LDB32(bsel, tn, s)                                                     \
  (*(const bf16x8*)&lds[((bsel) << 15) + ((2 + (wc >> 1)) << 13) +             \
                        ((wc & 1) << 12) + ((tn) << 11) + rowA +               \
                        (((((s) << 1) | hi) ^ sw) << 3)])

#define MFMA32(a, b, c) __builtin_amdgcn_mfma_f32_32x32x16_bf16((a), (b), (c), 0, 0, 0)

  // ---- prologue: tile0 (all 4 half-tiles) + tile1 A half-tiles ----
  STAGE2(0, 0, true) STAGE2(0, 1, true) STAGE2(0, 2, true) STAGE2(0, 3, true)
  STAGE2(1, 0, true) STAGE2(1, 1, true)
  asm volatile("s_waitcnt vmcnt(4)" ::: "memory");   // tile0 fully landed
  __builtin_amdgcn_s_barrier();

  f32x16 acc[4][2] = {};
  bf16x8 a01[2][4], a23[2][4], bq[4];

#pragma unroll 2
  for (int t = 0; t < NT; ++t) {
    const int bsel = t & 1;
    // ---------- phase 0: tiles (tm0,tm1)x(tn0); read a01 + bq(tn0); stage B2(t+1)
#pragma unroll
    for (int s = 0; s < 4; ++s) {
      a01[0][s] = LDA32(bsel, 0, s);
      a01[1][s] = LDA32(bsel, 1, s);
      bq[s] = LDB32(bsel, 0, s);
    }
    STAGE2(t + 1, 2, t + 1 < NT)
    __builtin_amdgcn_s_barrier();
    asm volatile("s_waitcnt lgkmcnt(0)" ::: "memory");
    __builtin_amdgcn_sched_barrier(0);
    __builtin_amdgcn_s_setprio(1);
#pragma unroll
    for (int s = 0; s < 4; ++s) {
      acc[0][0] = MFMA32(a01[0][s], bq[s], acc[0][0]);
      acc[1][0] = MFMA32(a01[1][s], bq[s], acc[1][0]);
    }
    __builtin_amdgcn_s_setprio(0);
    __builtin_amdgcn_s_barrier();
    // ---------- phase 1: tiles (tm2,tm3)x(tn0); read a23; stage B3(t+1) ----
#pragma unroll
    for (int s = 0; s < 4; ++s) {
      a23[0][s] = LDA32(bsel, 2, s);
      a23[1][s] = LDA32(bsel, 3, s);
    }
    STAGE2(t + 1, 3, t + 1 < NT)
    __builtin_amdgcn_s_barrier();
    asm volatile("s_waitcnt lgkmcnt(0)" ::: "memory");
    __builtin_amdgcn_sched_barrier(0);
    __builtin_amdgcn_s_setprio(1);
#pragma unroll
    for (int s = 0; s < 4; ++s) {
      acc[2][0] = MFMA32(a23[0][s], bq[s], acc[2][0]);
      acc[3][0] = MFMA32(a23[1][s], bq[s], acc[3][0]);
    }
    __builtin_amdgcn_s_setprio(0);
    __builtin_amdgcn_s_barrier();
    // ---------- phase 2: tiles (tm2,tm3)x(tn1); read bq(tn1); stage A0(t+2) -
    // (all A reads of this buffer completed at phase-1 barrier)
#pragma unroll
    for (int s = 0; s < 4; ++s) bq[s] = LDB32(bsel, 1, s);
    STAGE2(t + 2, 0, t + 2 < NT)
    __builtin_amdgcn_s_barrier();
    asm volatile("s_waitcnt lgkmcnt(0)" ::: "memory");
    __builtin_amdgcn_sched_barrier(0);
    __builtin_amdgcn_s_setprio(1);
#pragma unroll
    for (int s = 0; s < 4; ++s) {
      acc[2][1] = MFMA32(a23[0][s], bq[s], acc[2][1]);
      acc[3][1] = MFMA32(a23[1][s], bq[s], acc[3][1]);
    }
    __builtin_amdgcn_s_setprio(0);
    __builtin_amdgcn_s_barrier();
    // ---------- phase 3: tiles (tm0,tm1)x(tn1); reuse a01,bq; stage A1(t+2) -
    STAGE2(t + 2, 1, t + 2 < NT)
    __builtin_amdgcn_s_barrier();
    __builtin_amdgcn_sched_barrier(0);
    __builtin_amdgcn_s_setprio(1);
#pragma unroll
    for (int s = 0; s < 4; ++s) {
      acc[0][1] = MFMA32(a01[0][s], bq[s], acc[0][1]);
      acc[1][1] = MFMA32(a01[1][s], bq[s], acc[1][1]);
    }
    __builtin_amdgcn_s_setprio(0);
    // counted drain: completes B(t+1) (A(t+1) is older in vmcnt order);
    // keeps A(t+2) (4 loads) in flight. Full drain only at pipeline end.
    if (t < NT - 2) {
      asm volatile("s_waitcnt vmcnt(4)" ::: "memory");
    } else if (t == NT - 2) {
      asm volatile("s_waitcnt vmcnt(0)" ::: "memory");
    }
    __builtin_amdgcn_s_barrier();
    __builtin_amdgcn_sched_barrier(0);
  }

  // ---- epilogue: bias + f32 store ----
  // 32x32 C/D: col = lane&31, row = (reg&3) + 8*(reg>>2) + 4*(lane>>5)
  const int colL = lane & 31;
  const int rowH = hi << 2;
#pragma unroll
  for (int tn = 0; tn < 2; ++tn) {
    const int n = n0 + wc * 64 + tn * 32 + colL;
    const float bv = bias[n];
#pragma unroll
    for (int tm = 0; tm < 4; ++tm) {
      const int mb = m0 + wr * 128 + tm * 32 + rowH;
#pragma unroll
      for (int r = 0; r < 16; ++r) {
        const int row = mb + (r & 3) + ((r >> 2) << 3);
        out[(size_t)row * OUT_F + n] = acc[tm][tn][r] + bv;
      }
    }
  }
#undef STAGE2
#undef LDA32
#undef LDB32
#undef MFMA32
}

extern "C" void kernel_launch(void* const* d_in, const int* in_sizes, int n_in,
                              void* d_out, int out_size, void* d_ws, size_t ws_size,
                              hipStream_t stream) {
  (void)in_sizes; (void)n_in; (void)out_size; (void)ws_size;
  const float* x     = (const float*)d_in[0];
  const float* amax  = (const float*)d_in[1];
  const float* bias  = (const float*)d_in[2];
  const float* ldw   = (const float*)d_in[3];
  const float* luw   = (const float*)d_in[4];
  const float* alpha = (const float*)d_in[5];
  const int*   q     = (const int*)d_in[6];
  float* out = (float*)d_out;

  unsigned short* Ap = (unsigned short*)d_ws;                 // [NTOK][KP] bf16
  unsigned short* Bp = Ap + (size_t)NTOK * KP;                // [OUT_F][KP] bf16

  k_prep_a<<<NTOK / 4, 256, 0, stream>>>(x, ldw, Ap);
  k_prep_b<<<OUT_F, 256, 0, stream>>>(q, amax, luw, alpha, Bp);
  k_gemm<<<dim3(OUT_F / BN, NTOK / BM), 512, 0, stream>>>(Ap, Bp, bias, out);
}

// Round 6
// 333.177 us; speedup vs baseline: 1.1159x; 1.1159x over previous
//
#include <hip/hip_runtime.h>

#define IN_F 4096
#define OUT_F 4096
#define RANK 16
#define NTOK 8192
#define KP 4160            // IN_F + 16 lora cols + 48 zero pad = 65 * 64
#define BK 64
#define NT (KP / BK)       // 65
#define BM 256
#define BN 256

typedef __bf16 bf16x8 __attribute__((ext_vector_type(8)));
typedef float f32x4 __attribute__((ext_vector_type(4)));

__device__ __forceinline__ unsigned short f2bf(float f) {
  unsigned int u = __float_as_uint(f);
  u += 0x7fffu + ((u >> 16) & 1u);   // round-to-nearest-even
  return (unsigned short)(u >> 16);
}

__device__ __forceinline__ void async_ld16(const void* g, void* l) {
  __builtin_amdgcn_global_load_lds(
      (const __attribute__((address_space(1))) unsigned int*)g,
      (__attribute__((address_space(3))) unsigned int*)l, 16, 0, 0);
}

__device__ const float NF4_TAB[16] = {
    -1.0f, -0.6961928009986877f, -0.5250730514526367f, -0.39491748809814453f,
    -0.28444138169288635f, -0.18477343022823334f, -0.09105003625154495f, 0.0f,
    0.07958029955625534f, 0.16093020141124725f, 0.24611230194568634f,
    0.33791524171829224f, 0.44070982933044434f, 0.5626170039176941f,
    0.7229568362236023f, 1.0f};

// ---------------- K1: x -> bf16 A', fused lora_down t = x @ Ld^T ----------------
__global__ __launch_bounds__(256) void k_prep_a(
    const float* __restrict__ x, const float* __restrict__ ldw,
    unsigned short* __restrict__ Ap) {
  const int tid = threadIdx.x;
  const int lane = tid & 63;
  const int w = tid >> 6;
  const int m0 = blockIdx.x * 4;

  float acc[4][4];
#pragma unroll
  for (int i = 0; i < 4; ++i)
#pragma unroll
    for (int rl = 0; rl < 4; ++rl) acc[i][rl] = 0.f;

  for (int c = 0; c < 16; ++c) {
    const int k0 = (c * 64 + lane) * 4;
    float4 xv[4];
#pragma unroll
    for (int i = 0; i < 4; ++i) {
      xv[i] = *(const float4*)&x[(size_t)(m0 + i) * IN_F + k0];
      if (w == i) {  // wave i writes row i's bf16 conversion (balanced)
        ushort4 s;
        s.x = f2bf(xv[i].x); s.y = f2bf(xv[i].y);
        s.z = f2bf(xv[i].z); s.w = f2bf(xv[i].w);
        *(ushort4*)&Ap[(size_t)(m0 + i) * KP + k0] = s;
      }
    }
#pragma unroll
    for (int rl = 0; rl < 4; ++rl) {
      float4 lv = *(const float4*)&ldw[(size_t)(w * 4 + rl) * IN_F + k0];
#pragma unroll
      for (int i = 0; i < 4; ++i)
        acc[i][rl] += xv[i].x * lv.x + xv[i].y * lv.y + xv[i].z * lv.z +
                      xv[i].w * lv.w;
    }
  }
#pragma unroll
  for (int i = 0; i < 4; ++i)
#pragma unroll
    for (int rl = 0; rl < 4; ++rl) {
      float v = acc[i][rl];
#pragma unroll
      for (int m = 1; m < 64; m <<= 1) v += __shfl_xor(v, m, 64);
      acc[i][rl] = v;
    }
  __shared__ float red[4][16];
  if (lane == 0) {
#pragma unroll
    for (int i = 0; i < 4; ++i)
#pragma unroll
      for (int rl = 0; rl < 4; ++rl) red[i][w * 4 + rl] = acc[i][rl];
  }
  __syncthreads();
  if (tid < 64) {  // lora columns 4096..4111
    Ap[(size_t)(m0 + (tid >> 4)) * KP + IN_F + (tid & 15)] =
        f2bf(red[tid >> 4][tid & 15]);
  } else {  // zero pad cols 4112..4159 : 4 rows x 48 cols = 192 elems
    const int t2 = tid - 64;
    if (t2 < 192)
      Ap[(size_t)(m0 + t2 / 48) * KP + IN_F + 16 + (t2 % 48)] = 0;
  }
}

// ---------------- K2: NF4 dequant -> bf16 B', append Lu*(alpha/r) ----------------
__global__ __launch_bounds__(256) void k_prep_b(
    const int* __restrict__ q, const float* __restrict__ amax,
    const float* __restrict__ luw, const float* __restrict__ alpha,
    unsigned short* __restrict__ Bp) {
  __shared__ float tab[16];
  const int tid = threadIdx.x;
  const int n = blockIdx.x;
  if (tid < 16) tab[tid] = NF4_TAB[tid];
  __syncthreads();
#pragma unroll
  for (int c = 0; c < 4; ++c) {
    const int k0 = (tid + 256 * c) * 4;
    int4 qv = *(const int4*)&q[(size_t)n * IN_F + k0];
    float am = amax[n * (IN_F / 64) + (k0 >> 6)];
    ushort4 s;
    s.x = f2bf(tab[qv.x] * am);
    s.y = f2bf(tab[qv.y] * am);
    s.z = f2bf(tab[qv.z] * am);
    s.w = f2bf(tab[qv.w] * am);
    *(ushort4*)&Bp[(size_t)n * KP + k0] = s;
  }
  if (tid < RANK) {
    float sc = alpha[0] * (1.0f / RANK);
    Bp[(size_t)n * KP + IN_F + tid] = f2bf(luw[n * RANK + tid] * sc);
  } else if (tid < 64) {  // zero pad cols 4112..4159
    Bp[(size_t)n * KP + IN_F + tid] = 0;
  }
}

// ---------------- K3: 256x256 8-phase bf16 MFMA GEMM (16x16x32) ----------------
// C[m,n] = sum_k A'[m,k] * B'[n,k] + bias[n]
// R3 structure (measured best: 260.8us, conflicts=0) with ONE change:
// the manual per-phase {lgkmcnt(0); sched_barrier(0)} walls are removed so the
// compiler emits fine-grained counted lgkmcnt waits; reads are ordered so the
// first MFMA group depends only on the earliest reads. This overlaps the LDS
// read stream (2304 cyc/tile/CU) with the MFMA window (2483 cyc/tile/CU)
// which were previously fully serialized (sum == measured 4816 cyc/tile).
// Race-safety (unchanged): staged regions' readers retire (data-dep waitcnt
// before consuming MFMA) >=1 barrier before the stage-issue point; tile-close
// keeps the hard vmcnt + barrier + sched_barrier(0) handoff.
__global__ __launch_bounds__(512, 1) void k_gemm(
    const unsigned short* __restrict__ Ap, const unsigned short* __restrict__ Bp,
    const float* __restrict__ bias, float* __restrict__ out) {
  __shared__ unsigned short lds[65536];  // 128 KiB
  const int tid = threadIdx.x;
  const int lane = tid & 63;
  const int w = tid >> 6;
  const int wr = w >> 2;       // 0..1
  const int wc = w & 3;        // 0..3

  // T1: XCD-aware block swizzle (nwg = 512, divisible by 8)
  const int nwg = gridDim.x * gridDim.y;           // 512
  const int flat = blockIdx.y * gridDim.x + blockIdx.x;
  const int cpx = nwg >> 3;
  const int swz = (flat & 7) * cpx + (flat >> 3);
  const int m0 = (swz / (OUT_F / BN)) * BM;
  const int n0 = (swz % (OUT_F / BN)) * BN;

  // staging: wave w covers half-tile rows w*16 + i*8 + (lane>>3), i=0,1
  // source col slot pre-swizzled: slot_src = (lane&7) ^ (row&7)
  const int srow = lane >> 3;                       // 0..7
  const int scol = (((lane & 7) ^ srow) << 3);      // bf16 elems
  const unsigned short* gA = Ap + (size_t)(m0 + (w << 4) + srow) * KP + scol;
  const unsigned short* gB = Bp + (size_t)(n0 + (w << 4) + srow) * KP + scol;
  unsigned short* const ldsw = lds + (w << 10);     // wave-uniform dest base

  // read offset: row = lane&15, col slot = (lane>>4) ^ (lane&7);
  // kc selects slot bit 2 via XOR (rdoff ^ (kc<<5))
  const int rdoff = ((lane & 15) << 6) + (((lane >> 4) ^ (lane & 7)) << 3);

#define STAGE2(tt, ht, cond)                                                   \
  if (cond) {                                                                  \
    const unsigned short* s_ =                                                 \
        ((ht) < 2 ? gA + (size_t)((ht) << 7) * KP                              \
                  : gB + (size_t)(((ht)-2) << 7) * KP) + (size_t)(tt)*BK;      \
    unsigned short* d_ = ldsw + ((((tt)&1) << 15) + ((ht) << 13));             \
    async_ld16(s_, d_);                                                        \
    async_ld16(s_ + (size_t)8 * KP, d_ + 512);                                 \
  }

#define LDA(bsel, mh, f, kc)                                                   \
  (*(const bf16x8*)&lds[((bsel) << 15) + (wr << 13) +                          \
                        (((mh)*64 + (f)*16) << 6) + (((kc) << 5) ^ rdoff)])
#define LDB(bsel, nh, g, kc)                                                   \
  (*(const bf16x8*)&lds[((bsel) << 15) + ((2 + (wc >> 1)) << 13) +             \
                        ((((wc & 1) * 64) + (nh)*32 + (g)*16) << 6) +          \
                        (((kc) << 5) ^ rdoff)])

#define MFMA(a, b, c) __builtin_amdgcn_mfma_f32_16x16x32_bf16((a), (b), (c), 0, 0, 0)

  // ---- prologue: tile0 (all 4 half-tiles) + tile1 A half-tiles ----
  STAGE2(0, 0, true) STAGE2(0, 1, true) STAGE2(0, 2, true) STAGE2(0, 3, true)
  STAGE2(1, 0, true) STAGE2(1, 1, true)
  asm volatile("s_waitcnt vmcnt(4)" ::: "memory");   // tile0 fully landed
  __builtin_amdgcn_s_barrier();

  f32x4 acc[8][4] = {};
  bf16x8 a0[4][2], a1[4][2], bq[2][2];

#pragma unroll 2
  for (int t = 0; t < NT; ++t) {
    const int bsel = t & 1;
    // ---- phase 0: quadrant (M0,N0); reads: bq first, then a0 f-major ----
#pragma unroll
    for (int g = 0; g < 2; ++g) {
      bq[g][0] = LDB(bsel, 0, g, 0);
      bq[g][1] = LDB(bsel, 0, g, 1);
    }
#pragma unroll
    for (int f = 0; f < 4; ++f) {
      a0[f][0] = LDA(bsel, 0, f, 0);
      a0[f][1] = LDA(bsel, 0, f, 1);
    }
    STAGE2(t + 1, 2, t + 1 < NT)
    __builtin_amdgcn_s_barrier();
    __builtin_amdgcn_s_setprio(1);
#pragma unroll
    for (int f = 0; f < 4; ++f)      // f=0 depends on reads 1-6 only:
#pragma unroll                       // compiler emits counted lgkmcnt
      for (int g = 0; g < 2; ++g) {
        acc[f][g] = MFMA(a0[f][0], bq[g][0], acc[f][g]);
        acc[f][g] = MFMA(a0[f][1], bq[g][1], acc[f][g]);
      }
    __builtin_amdgcn_s_setprio(0);
    __builtin_amdgcn_s_barrier();
    // ---- phase 1: quadrant (M1,N0); reads a1 f-major; stage B3(t+1) ----
#pragma unroll
    for (int f = 0; f < 4; ++f) {
      a1[f][0] = LDA(bsel, 1, f, 0);
      a1[f][1] = LDA(bsel, 1, f, 1);
    }
    STAGE2(t + 1, 3, t + 1 < NT)
    __builtin_amdgcn_s_barrier();
    __builtin_amdgcn_s_setprio(1);
#pragma unroll
    for (int f = 0; f < 4; ++f)
#pragma unroll
      for (int g = 0; g < 2; ++g) {
        acc[4 + f][g] = MFMA(a1[f][0], bq[g][0], acc[4 + f][g]);
        acc[4 + f][g] = MFMA(a1[f][1], bq[g][1], acc[4 + f][g]);
      }
    __builtin_amdgcn_s_setprio(0);
    __builtin_amdgcn_s_barrier();
    // ---- phase 2: quadrant (M1,N1); reads bq(N1); stage A0(t+2) ----
    // MFMA (g,kc)-major: group 1 depends only on bq[0][0] (read #1).
#pragma unroll
    for (int g = 0; g < 2; ++g) {
      bq[g][0] = LDB(bsel, 1, g, 0);
      bq[g][1] = LDB(bsel, 1, g, 1);
    }
    STAGE2(t + 2, 0, t + 2 < NT)
    __builtin_amdgcn_s_barrier();
    __builtin_amdgcn_s_setprio(1);
#pragma unroll
    for (int g = 0; g < 2; ++g)
#pragma unroll
      for (int kc = 0; kc < 2; ++kc)
#pragma unroll
        for (int f = 0; f < 4; ++f)
          acc[4 + f][2 + g] = MFMA(a1[f][kc], bq[g][kc], acc[4 + f][2 + g]);
    __builtin_amdgcn_s_setprio(0);
    __builtin_amdgcn_s_barrier();
    // ---- phase 3: quadrant (M0,N1); all in regs; stage A1(t+2) ----
    STAGE2(t + 2, 1, t + 2 < NT)
    __builtin_amdgcn_s_barrier();
    __builtin_amdgcn_s_setprio(1);
#pragma unroll
    for (int f = 0; f < 4; ++f)
#pragma unroll
      for (int g = 0; g < 2; ++g) {
        acc[f][2 + g] = MFMA(a0[f][0], bq[g][0], acc[f][2 + g]);
        acc[f][2 + g] = MFMA(a0[f][1], bq[g][1], acc[f][2 + g]);
      }
    __builtin_amdgcn_s_setprio(0);
    // counted drain (hard handoff): tile t+1 fully landed; keep A(t+2)
    // (4 loads) in flight. Full drain only when the pipeline is ending.
    if (t < NT - 2) {
      asm volatile("s_waitcnt vmcnt(4)" ::: "memory");
    } else if (t == NT - 2) {
      asm volatile("s_waitcnt vmcnt(0)" ::: "memory");
    }
    __builtin_amdgcn_s_barrier();
    __builtin_amdgcn_sched_barrier(0);
  }

  // ---- epilogue: bias + f32 store (C/D: col = lane&15, row = (lane>>4)*4+e) ----
  const int colL = lane & 15;
  const int rowG = lane >> 4;
#pragma unroll
  for (int nj = 0; nj < 4; ++nj) {
    const int n = n0 + wc * 64 + nj * 16 + colL;
    const float bv = bias[n];
#pragma unroll
    for (int mi = 0; mi < 8; ++mi) {
      const int mb = m0 + wr * 128 + mi * 16 + rowG * 4;
#pragma unroll
      for (int e = 0; e < 4; ++e)
        out[(size_t)(mb + e) * OUT_F + n] = acc[mi][nj][e] + bv;
    }
  }
#undef STAGE2
#undef LDA
#undef LDB
#undef MFMA
}

extern "C" void kernel_launch(void* const* d_in, const int* in_sizes, int n_in,
                              void* d_out, int out_size, void* d_ws, size_t ws_size,
                              hipStream_t stream) {
  (void)in_sizes; (void)n_in; (void)out_size; (void)ws_size;
  const float* x     = (const float*)d_in[0];
  const float* amax  = (const float*)d_in[1];
  const float* bias  = (const float*)d_in[2];
  const float* ldw   = (const float*)d_in[3];
  const float* luw   = (const float*)d_in[4];
  const float* alpha = (const float*)d_in[5];
  const int*   q     = (const int*)d_in[6];
  float* out = (float*)d_out;

  unsigned short* Ap = (unsigned short*)d_ws;                 // [NTOK][KP] bf16
  unsigned short* Bp = Ap + (size_t)NTOK * KP;                // [OUT_F][KP] bf16

  k_prep_a<<<NTOK / 4, 256, 0, stream>>>(x, ldw, Ap);
  k_prep_b<<<OUT_F, 256, 0, stream>>>(q, amax, luw, alpha, Bp);
  k_gemm<<<dim3(OUT_F / BN, NTOK / BM), 512, 0, stream>>>(Ap, Bp, bias, out);
}